// Round 15
// baseline (112.899 us; speedup 1.0000x reference)
//
#include <hip/hip_runtime.h>
#include <hip/hip_bf16.h>

#define NR 4096
#define DIM 1024
#define NCLS 512

typedef __attribute__((ext_vector_type(4))) float f32x4;
typedef __attribute__((ext_vector_type(8))) int v8i;

// fp4 e2m1 quantizer: values {0,.5,1,1.5,2,3,4,6}, round-to-nearest, saturate.
static __device__ __forceinline__ unsigned int q4(float v) {
  unsigned int s = (v < 0.f) ? 8u : 0u;
  float a = fabsf(v);
  unsigned int c;
  if (a < 0.25f) c = 0;
  else if (a < 0.75f) c = 1;
  else if (a < 1.25f) c = 2;
  else if (a < 1.75f) c = 3;
  else if (a < 2.5f) c = 4;
  else if (a < 3.5f) c = 5;
  else if (a < 5.0f) c = 6;
  else c = 7;
  return s | c;
}

// ---- kernel 1: fused prep (R14, validated; + zero done_cnt) ----------------
// TILE-MAJOR fp4 layout: tile (rowblk rb, K-chunk kt) contiguous 8KB:
//   addr = rb*65536 + kt*8192 + (row&127)*64 + pchunk
__global__ __launch_bounds__(256) void k_prep(const float* __restrict__ x,
                                              const int* __restrict__ y,
                                              const float* __restrict__ yp,
                                              unsigned char* __restrict__ xnp,
                                              int* __restrict__ cnt,
                                              int* __restrict__ fpos,
                                              float* __restrict__ slot0,
                                              float* __restrict__ ce,
                                              float* __restrict__ out,
                                              int* __restrict__ done_cnt) {
  const int b = blockIdx.x;
  const int tid = threadIdx.x;
  if (b < 1024) {
    int row = b * 4 + (tid >> 6);
    int lane = tid & 63;
    const float4* xr = reinterpret_cast<const float4*>(x + (size_t)row * DIM);
    float4 v[4];
    float s = 0.f;
#pragma unroll
    for (int it = 0; it < 4; ++it) {
      v[it] = xr[it * 64 + lane];
      s += v[it].x * v[it].x + v[it].y * v[it].y + v[it].z * v[it].z + v[it].w * v[it].w;
    }
#pragma unroll
    for (int d = 1; d < 64; d <<= 1) s += __shfl_xor(s, d);
    float inv = 32.0f / fmaxf(sqrtf(s), 1e-8f);  // fold SCALE=32 (exact pow2)
    unsigned char* xo = xnp + (size_t)(row >> 7) * 65536 + (size_t)(row & 127) * 64;
#pragma unroll
    for (int it = 0; it < 4; ++it) {
      int k0 = (it * 64 + lane) * 4;  // quad start, 4-aligned, within one group
      int kt = k0 >> 7;               // K-chunk (0..7)
      int pchunk = ((k0 >> 5) & 3) * 16 + ((k0 & 31) >> 1);
      unsigned int n0 = q4(v[it].x * inv), n1 = q4(v[it].y * inv),
                   n2 = q4(v[it].z * inv), n3 = q4(v[it].w * inv);
      unsigned short pk =
          (unsigned short)(n0 | (n1 << 4) | (n2 << 8) | (n3 << 12));
      *(unsigned short*)(xo + kt * 8192 + pchunk) = pk;
    }
  } else if (b < 2048) {
    int row = (b - 1024) * 4 + (tid >> 6);
    int lane = tid & 63;
    const float4* p = reinterpret_cast<const float4*>(yp + (size_t)row * NCLS);
    float4 v0 = p[lane], v1 = p[lane + 64];
    float m = fmaxf(fmaxf(fmaxf(v0.x, v0.y), fmaxf(v0.z, v0.w)),
                    fmaxf(fmaxf(v1.x, v1.y), fmaxf(v1.z, v1.w)));
#pragma unroll
    for (int d = 1; d < 64; d <<= 1) m = fmaxf(m, __shfl_xor(m, d));
    float s = __expf(v0.x - m) + __expf(v0.y - m) + __expf(v0.z - m) + __expf(v0.w - m) +
              __expf(v1.x - m) + __expf(v1.y - m) + __expf(v1.z - m) + __expf(v1.w - m);
#pragma unroll
    for (int d = 1; d < 64; d <<= 1) s += __shfl_xor(s, d);
    if (lane == 0) {
      float py = yp[(size_t)row * NCLS + y[row]];
      ce[row] = logf(s) + m - py;
    }
  } else {
    __shared__ int ys[NR];
    __shared__ int scnt[NCLS], sm1[NCLS], sm2[NCLS];
    for (int j = tid; j < NR; j += 256) ys[j] = y[j];
    for (int c = tid; c < NCLS; c += 256) { scnt[c] = 0; sm1[c] = NR; sm2[c] = NR; }
    __syncthreads();
    for (int i = tid; i < NR; i += 256) {
      int c = ys[i];
      atomicAdd(&scnt[c], 1);
      atomicMin(&sm1[c], i);
    }
    __syncthreads();
    for (int i = tid; i < NR; i += 256) {
      int c = ys[i];
      if (sm1[c] != i) atomicMin(&sm2[c], i);
    }
    __syncthreads();
    for (int i = tid; i < NR; i += 256) {
      int c = ys[i];
      int m1 = sm1[c];
      int j = (m1 == i) ? ((sm2[c] >= NR) ? -1 : sm2[c]) : m1;
      fpos[i] = j;
      slot0[i] = 0.f;
    }
    for (int c = tid; c < NCLS; c += 256) cnt[c] = scnt[c];
    if (tid == 0) { out[0] = 0.f; *done_cnt = 0; }
  }
}

// ---- kernel 2: TRIANGULAR deep-pipelined 128x128 MX-fp4 GEMM + FUSED FINAL -
// R14 gemm (4 LDS bufs, 3-ahead staging, vmcnt(4), tile-major coalesced
// stages, triangular 528 grid, row/col-sum epilogue) + last-block-done final
// reduction (kernels 3 -> 2; tests the fixed-per-launch-overhead hypothesis).
// Cross-block visibility: writers do __threadfence() + device-scope atomicAdd
// (release); finisher re-fences after observing count==527 (acquire). Value
// is independent of WHICH block finishes last -> deterministic output.

#define STAGE2(SLOT, KT)                                                         \
  {                                                                              \
    const char* _sa = (const char*)xnp + (size_t)rb * 65536 +                    \
        (size_t)(KT) * 8192 + swzoff;                                            \
    __builtin_amdgcn_global_load_lds(                                            \
        (const __attribute__((address_space(1))) void*)_sa,                      \
        (__attribute__((address_space(3))) void*)(lds + (SLOT) * 16384 +         \
                                                  tid * 16),                     \
        16, 0, 0);                                                               \
    const char* _sb = (const char*)xnp + (size_t)cb * 65536 +                    \
        (size_t)(KT) * 8192 + swzoff;                                            \
    __builtin_amdgcn_global_load_lds(                                            \
        (const __attribute__((address_space(1))) void*)_sb,                      \
        (__attribute__((address_space(3))) void*)(lds + (SLOT) * 16384 + 8192 +  \
                                                  tid * 16),                     \
        16, 0, 0);                                                               \
  }

__global__ __launch_bounds__(512, 2) void k_gemm(const unsigned char* __restrict__ xnp,
                                                 const int* __restrict__ y,
                                                 const int* __restrict__ fpos,
                                                 float* __restrict__ part,
                                                 float* __restrict__ slot0,
                                                 const int* __restrict__ cnt,
                                                 const float* __restrict__ ce,
                                                 float* __restrict__ out,
                                                 int* __restrict__ done_cnt) {
  __shared__ char lds[65536];
  const int tid = threadIdx.x;
  const int w = tid >> 6, lane = tid & 63;
  const int wr = w >> 2, wcn = w & 3;
  const int r0 = lane & 15, klo = lane >> 4;

  // triangular tile decode with XCD swizzle (528 = 8 * 66)
  const int bid = blockIdx.x;
  int t0 = (bid & 7) * 66 + (bid >> 3), rb = 0;
  while (t0 >= 32 - rb) { t0 -= 32 - rb; ++rb; }
  const int cb = rb + t0;
  const int rowbase = rb * 128, colbase = cb * 128;
  const bool offd = (rb != cb);

  const int kread = (klo * 16) ^ ((r0 & 3) << 4);
  const int ABaseW = wr * 4096 + r0 * 64 + kread;           // within A-half
  const int BBaseW = 8192 + wcn * 2048 + r0 * 64 + kread;   // within buf (B at +8KB)

  // inverse-swizzled stage offset within the contiguous 8KB tile
  const int D = tid * 16;
  const int swzoff = D ^ (((D >> 6) & 3) << 4);   // involution, bits 4-5 only

  f32x4 acc[4][2] = {};

  // prologue: stage chunks 0,1,2 -> slots 0,1,2 (6 loads in flight)
  STAGE2(0, 0)
  STAGE2(1, 1)
  STAGE2(2, 2)

#pragma unroll
  for (int t = 0; t < 8; ++t) {
    asm volatile("s_waitcnt vmcnt(4)" ::: "memory");  // chunk-t loads landed
    __builtin_amdgcn_s_barrier();                     // all waves see them
    {
      const int kt = (t + 3 < 8) ? t + 3 : 7;         // clamped dead-slot tail
      STAGE2((t + 3) & 3, kt)
    }
    const int bufb = (t & 3) * 16384;
    v8i afr[4], bfr[2];
#pragma unroll
    for (int mm = 0; mm < 4; ++mm) {
      int4 t4 = *(const int4*)(lds + bufb + ABaseW + mm * 1024);
      v8i tv = {t4.x, t4.y, t4.z, t4.w, 0, 0, 0, 0};
      afr[mm] = tv;
    }
#pragma unroll
    for (int nf = 0; nf < 2; ++nf) {
      int4 t4 = *(const int4*)(lds + bufb + BBaseW + nf * 1024);
      v8i tv = {t4.x, t4.y, t4.z, t4.w, 0, 0, 0, 0};
      bfr[nf] = tv;
    }
    __builtin_amdgcn_s_setprio(1);
#pragma unroll
    for (int mm = 0; mm < 4; ++mm)
#pragma unroll
      for (int nf = 0; nf < 2; ++nf)
        acc[mm][nf] = __builtin_amdgcn_mfma_scale_f32_16x16x128_f8f6f4(
            afr[mm], bfr[nf], acc[mm][nf], 4, 4,
            0, 0x7F7F7F7F, 0, 0x7F7F7F7F);
    __builtin_amdgcn_s_setprio(0);
  }

  // drain in-flight stages before repurposing LDS
  asm volatile("s_waitcnt vmcnt(0)" ::: "memory");
  __syncthreads();

  // ---- epilogue: masked exp row+col sums, slot0 scatter both sides ----
  // sim = acc/1024 (SCALE=32 squared), sv = (sim+1)*0.25 = acc/4096 + 0.25
  int* yrow_s = (int*)lds;             // 128 ints
  int* ycol_s = (int*)(lds + 512);     // 128 ints
  int* frow_s = (int*)(lds + 1024);    // 128 ints
  int* fcol_s = (int*)(lds + 1536);    // 128 ints
  float* rsum = (float*)(lds + 2048);  // 128*4 floats
  float* csum = (float*)(lds + 4096);  // 128*2 floats
  if (tid < 128) {
    yrow_s[tid] = y[rowbase + tid];
    frow_s[tid] = fpos[rowbase + tid];
  } else if (tid < 256) {
    ycol_s[tid - 128] = y[colbase + tid - 128];
    fcol_s[tid - 128] = fpos[colbase + tid - 128];
  }
  __syncthreads();

  float csn[2] = {0.f, 0.f};
#pragma unroll
  for (int m = 0; m < 4; ++m) {
    float rs[4] = {0.f, 0.f, 0.f, 0.f};
    int rloc[4], yr[4], fr[4];
#pragma unroll
    for (int reg = 0; reg < 4; ++reg) {
      rloc[reg] = wr * 64 + m * 16 + klo * 4 + reg;
      yr[reg] = yrow_s[rloc[reg]];
      fr[reg] = frow_s[rloc[reg]];
    }
#pragma unroll
    for (int nf = 0; nf < 2; ++nf) {
      int cl = wcn * 32 + nf * 16 + r0;
      int yc = ycol_s[cl];
      int fc = fcol_s[cl];
      int gc = colbase + cl;
#pragma unroll
      for (int reg = 0; reg < 4; ++reg) {
        float sv = acc[m][nf][reg] * (1.0f / 4096.f) + 0.25f;
        float e = (yr[reg] == yc) ? 0.f : __expf(sv);
        rs[reg] += e;
        csn[nf] += e;
        int gr = rowbase + rloc[reg];
        if (fr[reg] == gc) slot0[gr] = sv;
        if (offd && fc == gr) slot0[gc] = sv;
      }
    }
#pragma unroll
    for (int d = 1; d < 16; d <<= 1)
#pragma unroll
      for (int reg = 0; reg < 4; ++reg) rs[reg] += __shfl_xor(rs[reg], d);
    if (r0 == 0) {
#pragma unroll
      for (int reg = 0; reg < 4; ++reg)
        rsum[rloc[reg] * 4 + wcn] = rs[reg];
    }
  }
  // col-sum reduce across the 4 klo row-groups (lanes sharing r0)
#pragma unroll
  for (int nf = 0; nf < 2; ++nf) {
    csn[nf] += __shfl_xor(csn[nf], 16);
    csn[nf] += __shfl_xor(csn[nf], 32);
  }
  if (klo == 0) {
#pragma unroll
    for (int nf = 0; nf < 2; ++nf)
      csum[(wcn * 32 + nf * 16 + r0) * 2 + wr] = csn[nf];
  }
  __syncthreads();
  if (tid < 128) {
    part[(size_t)cb * NR + rowbase + tid] =
        rsum[tid * 4] + rsum[tid * 4 + 1] + rsum[tid * 4 + 2] + rsum[tid * 4 + 3];
    if (offd)
      part[(size_t)rb * NR + colbase + tid] = csum[tid * 2] + csum[tid * 2 + 1];
  }

  // ---- fused final: last block to finish does the loss reduction ----
  __shared__ int is_last;
  __threadfence();            // release our part/slot0 writes (device scope)
  __syncthreads();
  if (tid == 0) is_last = (atomicAdd(done_cnt, 1) == 527);
  __syncthreads();
  if (!is_last) return;
  __threadfence();            // acquire all blocks' part/slot0 writes

  float* red = (float*)(lds + 8192);  // 512 floats
  float accv = 0.f;
  for (int r = tid; r < NR; r += 512) {
    float S = 0.f;
#pragma unroll
    for (int bb = 0; bb < 32; ++bb) S += part[(size_t)bb * NR + r];
    float s0 = slot0[r];
    float zeros = 4094.0f + (float)cnt[y[r]];  // 8190 - (4096 - cnt)
    float cl = logf(__expf(s0) + S + zeros) - s0;
    accv += 0.5f * (cl + ce[r]);
  }
  red[tid] = accv;
  __syncthreads();
  for (int s = 256; s > 0; s >>= 1) {
    if (tid < s) red[tid] += red[tid + s];
    __syncthreads();
  }
  if (tid == 0) out[0] = red[0] / (float)NR;
}

extern "C" void kernel_launch(void* const* d_in, const int* in_sizes, int n_in,
                              void* d_out, int out_size, void* d_ws, size_t ws_size,
                              hipStream_t stream) {
  const float* x = (const float*)d_in[0];
  const int* y = (const int*)d_in[1];
  const float* yp = (const float*)d_in[2];
  float* out = (float*)d_out;

  char* w = (char*)d_ws;
  unsigned char* xnp = (unsigned char*)w;    // 4096*512 = 2097152 B
  int* cnt = (int*)(w + 2097152);            // 2048 B
  int* fpos = (int*)(w + 2099200);           // 16384 B
  float* slot0 = (float*)(w + 2115584);      // 16384 B
  float* part = (float*)(w + 2131968);       // 32*4096*4 = 524288 B
  float* ce = (float*)(w + 2656256);         // 16384 B
  int* done_cnt = (int*)(w + 2672640);       // 4 B

  k_prep<<<2049, 256, 0, stream>>>(x, y, yp, xnp, cnt, fpos, slot0, ce, out, done_cnt);
  k_gemm<<<528, 512, 0, stream>>>(xnp, y, fpos, part, slot0, cnt, ce, out, done_cnt);
}

// Round 16
// 45.021 us; speedup vs baseline: 2.5077x; 2.5077x over previous
//
#include <hip/hip_runtime.h>
#include <hip/hip_bf16.h>

#define NR 4096
#define DIM 1024
#define NCLS 512

typedef __attribute__((ext_vector_type(4))) float f32x4;
typedef __attribute__((ext_vector_type(8))) int v8i;

// fp4 e2m1 quantizer: values {0,.5,1,1.5,2,3,4,6}, round-to-nearest, saturate.
static __device__ __forceinline__ unsigned int q4(float v) {
  unsigned int s = (v < 0.f) ? 8u : 0u;
  float a = fabsf(v);
  unsigned int c;
  if (a < 0.25f) c = 0;
  else if (a < 0.75f) c = 1;
  else if (a < 1.25f) c = 2;
  else if (a < 1.75f) c = 3;
  else if (a < 2.5f) c = 4;
  else if (a < 3.5f) c = 5;
  else if (a < 5.0f) c = 6;
  else c = 7;
  return s | c;
}

// ---- kernel 1: fused prep (R11, numerics validated) ------------------------
// Row-major fp4 layout per row (512 B): 8 K-chunks of 64 B; within a chunk,
// group g=(k>>5)&3 at bytes [g*16,g*16+16), element k at byte (k&31)>>1,
// nibble k&1 (16B at g*16 = one MFMA fragment k-block).
__global__ __launch_bounds__(256) void k_prep(const float* __restrict__ x,
                                              const int* __restrict__ y,
                                              const float* __restrict__ yp,
                                              unsigned char* __restrict__ xnp,
                                              int* __restrict__ cnt,
                                              int* __restrict__ fpos,
                                              float* __restrict__ slot0,
                                              float* __restrict__ ce,
                                              float* __restrict__ out) {
  const int b = blockIdx.x;
  const int tid = threadIdx.x;
  if (b < 1024) {
    int row = b * 4 + (tid >> 6);
    int lane = tid & 63;
    const float4* xr = reinterpret_cast<const float4*>(x + (size_t)row * DIM);
    float4 v[4];
    float s = 0.f;
#pragma unroll
    for (int it = 0; it < 4; ++it) {
      v[it] = xr[it * 64 + lane];
      s += v[it].x * v[it].x + v[it].y * v[it].y + v[it].z * v[it].z + v[it].w * v[it].w;
    }
#pragma unroll
    for (int d = 1; d < 64; d <<= 1) s += __shfl_xor(s, d);
    float inv = 32.0f / fmaxf(sqrtf(s), 1e-8f);  // fold SCALE=32 (exact pow2)
    unsigned char* xo = xnp + (size_t)row * 512;
#pragma unroll
    for (int it = 0; it < 4; ++it) {
      int k0 = (it * 64 + lane) * 4;  // quad start, 4-aligned, within one group
      int pos = (k0 >> 7) * 64 + ((k0 >> 5) & 3) * 16 + ((k0 & 31) >> 1);
      unsigned int n0 = q4(v[it].x * inv), n1 = q4(v[it].y * inv),
                   n2 = q4(v[it].z * inv), n3 = q4(v[it].w * inv);
      unsigned short pk =
          (unsigned short)(n0 | (n1 << 4) | (n2 << 8) | (n3 << 12));
      *(unsigned short*)(xo + pos) = pk;
    }
  } else if (b < 2048) {
    int row = (b - 1024) * 4 + (tid >> 6);
    int lane = tid & 63;
    const float4* p = reinterpret_cast<const float4*>(yp + (size_t)row * NCLS);
    float4 v0 = p[lane], v1 = p[lane + 64];
    float m = fmaxf(fmaxf(fmaxf(v0.x, v0.y), fmaxf(v0.z, v0.w)),
                    fmaxf(fmaxf(v1.x, v1.y), fmaxf(v1.z, v1.w)));
#pragma unroll
    for (int d = 1; d < 64; d <<= 1) m = fmaxf(m, __shfl_xor(m, d));
    float s = __expf(v0.x - m) + __expf(v0.y - m) + __expf(v0.z - m) + __expf(v0.w - m) +
              __expf(v1.x - m) + __expf(v1.y - m) + __expf(v1.z - m) + __expf(v1.w - m);
#pragma unroll
    for (int d = 1; d < 64; d <<= 1) s += __shfl_xor(s, d);
    if (lane == 0) {
      float py = yp[(size_t)row * NCLS + y[row]];
      ce[row] = logf(s) + m - py;
    }
  } else {
    __shared__ int ys[NR];
    __shared__ int scnt[NCLS], sm1[NCLS], sm2[NCLS];
    for (int j = tid; j < NR; j += 256) ys[j] = y[j];
    for (int c = tid; c < NCLS; c += 256) { scnt[c] = 0; sm1[c] = NR; sm2[c] = NR; }
    __syncthreads();
    for (int i = tid; i < NR; i += 256) {
      int c = ys[i];
      atomicAdd(&scnt[c], 1);
      atomicMin(&sm1[c], i);
    }
    __syncthreads();
    for (int i = tid; i < NR; i += 256) {
      int c = ys[i];
      if (sm1[c] != i) atomicMin(&sm2[c], i);
    }
    __syncthreads();
    for (int i = tid; i < NR; i += 256) {
      int c = ys[i];
      int m1 = sm1[c];
      int j = (m1 == i) ? ((sm2[c] >= NR) ? -1 : sm2[c]) : m1;
      fpos[i] = j;
      slot0[i] = 0.f;
    }
    for (int c = tid; c < NCLS; c += 256) cnt[c] = scnt[c];
    if (tid == 0) out[0] = 0.f;
  }
}

// ---- kernel 2: TRIANGULAR 4-phase 128x128 MX-fp4 GEMM + row/col-sum epilogue
// R11 exact (best measured, 45.2us total) MINUS the s_setprio pair (T5 is
// null-to-negative in lockstep non-8-phase GEMM schedules, m190).
// Only tiles cb >= rb (528 of 1024). Tile (rb,cb): row-sums ->
// part[cb][rowbase+r]; col-sums (rb!=cb) -> part[rb][colbase+c]; slot0
// scatter on both sides. LDS 32KB: 2 bufs x {A(8KB),B(8KB)}; 2 blocks/CU.

#define STAGE(SSLOT, GROWBASE, KT)                                               \
  {                                                                              \
    const char* _src = (const char*)xnp +                                        \
        (size_t)((GROWBASE) + srow) * 512 + (size_t)(KT) * 64 + scol;            \
    __builtin_amdgcn_global_load_lds(                                            \
        (const __attribute__((address_space(1))) void*)_src,                     \
        (__attribute__((address_space(3))) void*)(lds + (SSLOT) + tid * 16),     \
        16, 0, 0);                                                               \
  }

#define PHASE(BUFB, RP, LOADB, SSLOT, SBASE, SKT, VM)                            \
  {                                                                              \
    _Pragma("unroll") for (int mm = 0; mm < 2; ++mm) {                           \
      int4 t4 = *(const int4*)(lds + (BUFB) + ABaseW +                           \
                               ((RP) * 2 + mm) * 1024);                          \
      v8i tv = {t4.x, t4.y, t4.z, t4.w, 0, 0, 0, 0};                             \
      afr[mm] = tv;                                                              \
    }                                                                            \
    if (LOADB) {                                                                 \
      _Pragma("unroll") for (int nf = 0; nf < 2; ++nf) {                         \
        int4 t4 = *(const int4*)(lds + (BUFB) + BBaseW + nf * 1024);             \
        v8i tv = {t4.x, t4.y, t4.z, t4.w, 0, 0, 0, 0};                           \
        bfr[nf] = tv;                                                            \
      }                                                                          \
    }                                                                            \
    STAGE(SSLOT, SBASE, SKT)                                                     \
    if (VM) asm volatile("s_waitcnt vmcnt(1)" ::: "memory");                     \
    __builtin_amdgcn_s_barrier();                                                \
    asm volatile("s_waitcnt lgkmcnt(0)" ::: "memory");                           \
    __builtin_amdgcn_sched_barrier(0);                                           \
    _Pragma("unroll") for (int mm = 0; mm < 2; ++mm)                             \
      _Pragma("unroll") for (int nf = 0; nf < 2; ++nf)                           \
        acc[(RP) * 2 + mm][nf] = __builtin_amdgcn_mfma_scale_f32_16x16x128_f8f6f4( \
            afr[mm], bfr[nf], acc[(RP) * 2 + mm][nf], 4, 4,                      \
            0, 0x7F7F7F7F, 0, 0x7F7F7F7F);                                       \
    __builtin_amdgcn_sched_barrier(0);                                           \
    __builtin_amdgcn_s_barrier();                                                \
  }

__global__ __launch_bounds__(512, 2) void k_gemm(const unsigned char* __restrict__ xnp,
                                                 const int* __restrict__ y,
                                                 const int* __restrict__ fpos,
                                                 float* __restrict__ part,
                                                 float* __restrict__ slot0) {
  __shared__ char lds[32768];
  const int tid = threadIdx.x;
  const int w = tid >> 6, lane = tid & 63;
  const int wr = w >> 2, wcn = w & 3;
  const int r0 = lane & 15, klo = lane >> 4;

  // triangular tile decode with XCD swizzle (528 = 8 * 66)
  const int bid = blockIdx.x;
  int t = (bid & 7) * 66 + (bid >> 3), rb = 0;
  while (t >= 32 - rb) { t -= 32 - rb; ++rb; }
  const int cb = rb + t;
  const int rowbase = rb * 128, colbase = cb * 128;
  const bool offd = (rb != cb);

  const int kread = (klo * 16) ^ ((r0 & 3) << 4);
  const int ABaseW = wr * 4096 + r0 * 64 + kread;
  const int BBaseW = 8192 + wcn * 2048 + r0 * 64 + kread;

  int srow, scol;
  {
    int D = tid * 16;                          // linear dest in tile
    int L = D ^ (((D >> 6) & 3) << 4);         // inverse swizzle (involution)
    srow = L >> 6;
    scol = L & 63;
  }

  f32x4 acc[4][2] = {};

  // prologue: A(0),B(0) -> buf0; B(1) -> buf1-B
  STAGE(8192, colbase, 0)           // B(0) -> b0B
  STAGE(0, rowbase, 0)              // A(0) -> b0A
  STAGE(24576, colbase, 1)          // B(1) -> b1B
  asm volatile("s_waitcnt vmcnt(1)" ::: "memory");
  __builtin_amdgcn_s_barrier();

  for (int i = 0; i < 4; ++i) {
    const int t1 = 2 * i + 1;
    const int tn = (2 * i + 2 < 8) ? 2 * i + 2 : 7;   // clamped dead-slot
    const int tn1 = (2 * i + 3 < 8) ? 2 * i + 3 : 7;  // stages keep counts
    v8i afr[2], bfr[2];
    PHASE(0,     0, 1, 16384, rowbase, t1, 0)   // p0
    PHASE(0,     1, 0, 8192,  colbase, tn, 1)   // p1
    PHASE(16384, 0, 1, 0,     rowbase, tn, 0)   // p2
    PHASE(16384, 1, 0, 24576, colbase, tn1, 1)  // p3
  }

  // drain in-flight stages before repurposing LDS
  asm volatile("s_waitcnt vmcnt(0)" ::: "memory");
  __syncthreads();

  // ---- epilogue: masked exp row+col sums, slot0 scatter both sides ----
  // sim = acc/1024 (SCALE=32 squared), sv = (sim+1)*0.25 = acc/4096 + 0.25
  int* yrow_s = (int*)lds;             // 128 ints
  int* ycol_s = (int*)(lds + 512);     // 128 ints
  int* frow_s = (int*)(lds + 1024);    // 128 ints
  int* fcol_s = (int*)(lds + 1536);    // 128 ints
  float* rsum = (float*)(lds + 2048);  // 128*4 floats
  float* csum = (float*)(lds + 4096);  // 128*2 floats
  if (tid < 128) {
    yrow_s[tid] = y[rowbase + tid];
    frow_s[tid] = fpos[rowbase + tid];
  } else if (tid < 256) {
    ycol_s[tid - 128] = y[colbase + tid - 128];
    fcol_s[tid - 128] = fpos[colbase + tid - 128];
  }
  __syncthreads();

  float csn[2] = {0.f, 0.f};
#pragma unroll
  for (int m = 0; m < 4; ++m) {
    float rs[4] = {0.f, 0.f, 0.f, 0.f};
    int rloc[4], yr[4], fr[4];
#pragma unroll
    for (int reg = 0; reg < 4; ++reg) {
      rloc[reg] = wr * 64 + m * 16 + klo * 4 + reg;
      yr[reg] = yrow_s[rloc[reg]];
      fr[reg] = frow_s[rloc[reg]];
    }
#pragma unroll
    for (int nf = 0; nf < 2; ++nf) {
      int cl = wcn * 32 + nf * 16 + r0;
      int yc = ycol_s[cl];
      int fc = fcol_s[cl];
      int gc = colbase + cl;
#pragma unroll
      for (int reg = 0; reg < 4; ++reg) {
        float sv = acc[m][nf][reg] * (1.0f / 4096.f) + 0.25f;
        float e = (yr[reg] == yc) ? 0.f : __expf(sv);
        rs[reg] += e;
        csn[nf] += e;
        int gr = rowbase + rloc[reg];
        if (fr[reg] == gc) slot0[gr] = sv;
        if (offd && fc == gr) slot0[gc] = sv;
      }
    }
#pragma unroll
    for (int d = 1; d < 16; d <<= 1)
#pragma unroll
      for (int reg = 0; reg < 4; ++reg) rs[reg] += __shfl_xor(rs[reg], d);
    if (r0 == 0) {
#pragma unroll
      for (int reg = 0; reg < 4; ++reg)
        rsum[rloc[reg] * 4 + wcn] = rs[reg];
    }
  }
  // col-sum reduce across the 4 klo row-groups (lanes sharing r0)
#pragma unroll
  for (int nf = 0; nf < 2; ++nf) {
    csn[nf] += __shfl_xor(csn[nf], 16);
    csn[nf] += __shfl_xor(csn[nf], 32);
  }
  if (klo == 0) {
#pragma unroll
    for (int nf = 0; nf < 2; ++nf)
      csum[(wcn * 32 + nf * 16 + r0) * 2 + wr] = csn[nf];
  }
  __syncthreads();
  if (tid < 128) {
    part[(size_t)cb * NR + rowbase + tid] =
        rsum[tid * 4] + rsum[tid * 4 + 1] + rsum[tid * 4 + 2] + rsum[tid * 4 + 3];
    if (offd)
      part[(size_t)rb * NR + colbase + tid] = csum[tid * 2] + csum[tid * 2 + 1];
  }
}

// ---- kernel 3: final loss reduction ----------------------------------------
__global__ __launch_bounds__(256) void k_final(const float* __restrict__ part,
                                               const float* __restrict__ slot0,
                                               const int* __restrict__ cnt,
                                               const int* __restrict__ y,
                                               const float* __restrict__ ce,
                                               float* __restrict__ out) {
  __shared__ float red[256];
  const int tid = threadIdx.x;
  const int r = blockIdx.x * 256 + tid;
  float S = 0.f;
#pragma unroll
  for (int b = 0; b < 32; ++b) S += part[(size_t)b * NR + r];
  float s0 = slot0[r];
  float zeros = 4094.0f + (float)cnt[y[r]];  // 8190 - (4096 - cnt)
  float cl = logf(__expf(s0) + S + zeros) - s0;
  red[tid] = 0.5f * (cl + ce[r]);
  __syncthreads();
  for (int s = 128; s > 0; s >>= 1) {
    if (tid < s) red[tid] += red[tid + s];
    __syncthreads();
  }
  if (tid == 0) atomicAdd(out, red[0] / (float)NR);
}

extern "C" void kernel_launch(void* const* d_in, const int* in_sizes, int n_in,
                              void* d_out, int out_size, void* d_ws, size_t ws_size,
                              hipStream_t stream) {
  const float* x = (const float*)d_in[0];
  const int* y = (const int*)d_in[1];
  const float* yp = (const float*)d_in[2];
  float* out = (float*)d_out;

  char* w = (char*)d_ws;
  unsigned char* xnp = (unsigned char*)w;    // 4096*512 = 2097152 B
  int* cnt = (int*)(w + 2097152);            // 2048 B
  int* fpos = (int*)(w + 2099200);           // 16384 B
  float* slot0 = (float*)(w + 2115584);      // 16384 B
  float* part = (float*)(w + 2131968);       // 32*4096*4 = 524288 B
  float* ce = (float*)(w + 2656256);         // 16384 B

  k_prep<<<2049, 256, 0, stream>>>(x, y, yp, xnp, cnt, fpos, slot0, ce, out);
  k_gemm<<<528, 512, 0, stream>>>(xnp, y, fpos, part, slot0);
  k_final<<<16, 256, 0, stream>>>(part, slot0, cnt, y, ce, out);
}